// Round 3
// baseline (236.744 us; speedup 1.0000x reference)
//
#include <hip/hip_runtime.h>
#include <hip/hip_bf16.h>

// CRF NLL + argmax for B=2048, T=1024, K=8.
// Exp-space chunked forward algorithm:
//   p_t = D_t * E^T * p_{t-1},  E = exp(transitions), D_t = diag(exp(score_t))
// NC=64 chunks of 16 steps; 8 threads per chunk (one column each), per-column
// log-scales. Row-major matrices so combine (8 lanes/batch, lane j = row j)
// reads coalesced. Explicit software prefetch in chunk & combine loops.

namespace {

constexpr int B = 2048;
constexpr int T = 1024;

__device__ __forceinline__ float max8(const float* a) {
  return fmaxf(fmaxf(fmaxf(a[0], a[1]), fmaxf(a[2], a[3])),
               fmaxf(fmaxf(a[4], a[5]), fmaxf(a[6], a[7])));
}

// ---------------------------------------------------------------------------
// Kernel 1: 4 timesteps per thread: argmax prediction + numerator partials.
// Thread handles t0..t0+3 of one batch; wave covers 256 consecutive t.
// ---------------------------------------------------------------------------
__global__ __launch_bounds__(256) void pred_num_kernel(
    const float* __restrict__ log_p, const float* __restrict__ score,
    const float* __restrict__ trans, const float* __restrict__ start_tr,
    const float* __restrict__ end_tr, const int* __restrict__ tags,
    const int* __restrict__ seq_l, float* __restrict__ out_pred,
    float* __restrict__ ws_num) {
  int tid = blockIdx.x * blockDim.x + threadIdx.x;
  int g0 = tid << 2;          // first (b,t) flat index
  int b = g0 >> 10;
  int t0 = g0 & (T - 1);
  int L = seq_l[b];

  // vectorized loads: 8x float4 of log_p, 1x int4 of tags
  const float4* lp = reinterpret_cast<const float4*>(log_p) + (g0 << 1);
  float4 u[8];
#pragma unroll
  for (int r = 0; r < 8; ++r) u[r] = lp[r];
  int4 tg4 = *reinterpret_cast<const int4*>(tags + g0);
  int tg[4] = {tg4.x, tg4.y, tg4.z, tg4.w};
  int prev0 = (t0 == 0) ? 0 : tags[g0 - 1];  // predecessor tag for r==0

  float contrib = 0.0f;
#pragma unroll
  for (int r = 0; r < 4; ++r) {
    float v[8] = {u[2 * r].x, u[2 * r].y, u[2 * r].z, u[2 * r].w,
                  u[2 * r + 1].x, u[2 * r + 1].y, u[2 * r + 1].z,
                  u[2 * r + 1].w};
    int best = 0;
    float bv = v[0];
#pragma unroll
    for (int j = 1; j < 8; ++j) {
      if (v[j] > bv) { bv = v[j]; best = j; }  // first max == jnp.argmax
    }
    int t = t0 + r;
    bool act = (t < L);
    out_pred[g0 + r] = act ? (float)best : 0.0f;
    if (act) {
      int tgr = tg[r];
      float csum = score[(size_t)(g0 + r) * 8 + tgr];
      if (t == 0)
        csum += start_tr[tgr];
      else
        csum += trans[((r == 0) ? prev0 : tg[r - 1]) * 8 + tgr];
      if (t == L - 1) csum += end_tr[tgr];
      contrib += csum;
    }
  }
#pragma unroll
  for (int off = 32; off >= 1; off >>= 1) contrib += __shfl_down(contrib, off);
  if ((threadIdx.x & 63) == 0) atomicAdd(&ws_num[b], contrib);
}

// ---------------------------------------------------------------------------
// Kernel 2: chunk transfer matrices with software-prefetched score loads.
// thread -> (b, c, k): column k of A_c = M_{te-1} ... M_{ts}.
// Stored ROW-major: wsA[(b*NC+c)*64 + j*8 + k].
// ---------------------------------------------------------------------------
template <int NC, int LOG_NC>
__global__ __launch_bounds__(256) void chunk_kernel(
    const float* __restrict__ score, const float* __restrict__ trans,
    const int* __restrict__ seq_l, float* __restrict__ wsA,
    float* __restrict__ wsS) {
  constexpr int CL = T / NC;
  int g = blockIdx.x * blockDim.x + threadIdx.x;
  int k = g & 7;
  int c = (g >> 3) & (NC - 1);
  int b = g >> (3 + LOG_NC);

  float E[8][8];
#pragma unroll
  for (int i = 0; i < 8; ++i)
#pragma unroll
    for (int j = 0; j < 8; ++j) E[i][j] = __expf(trans[i * 8 + j]);

  float a[8];
#pragma unroll
  for (int j = 0; j < 8; ++j) a[j] = (j == k) ? 1.0f : 0.0f;
  float sig = 0.0f;

  int L = seq_l[b];
  int t0 = c * CL;
  int ts = (c == 0) ? 1 : t0;  // t=0 folded into p0 in combine
  int te = min(t0 + CL, L);
  int n = te - ts;
  const float* sp = score + ((size_t)b * T + ts) * 8;

  float4 nA, nB;
  if (n > 0) {
    nA = *reinterpret_cast<const float4*>(sp);
    nB = *reinterpret_cast<const float4*>(sp + 4);
  }
  for (int it = 0; it < n; ++it) {
    float4 sA = nA, sB = nB;
    if (it + 1 < n) {  // prefetch next step before this step's FMAs
      nA = *reinterpret_cast<const float4*>(sp + 8);
      nB = *reinterpret_cast<const float4*>(sp + 12);
    }
    sp += 8;
    float em[8] = {__expf(sA.x), __expf(sA.y), __expf(sA.z), __expf(sA.w),
                   __expf(sB.x), __expf(sB.y), __expf(sB.z), __expf(sB.w)};
    float na[8];
#pragma unroll
    for (int j = 0; j < 8; ++j) {
      float acc = E[0][j] * a[0];
#pragma unroll
      for (int i = 1; i < 8; ++i) acc = fmaf(E[i][j], a[i], acc);
      na[j] = em[j] * acc;
    }
#pragma unroll
    for (int j = 0; j < 8; ++j) a[j] = na[j];
    if ((it & 7) == 7) {
      float mm = max8(a);
      float r = __builtin_amdgcn_rcpf(mm);
#pragma unroll
      for (int j = 0; j < 8; ++j) a[j] *= r;
      sig += __logf(mm);
    }
  }
  {
    float mm = max8(a);
    if (mm > 0.0f) {
      float r = __builtin_amdgcn_rcpf(mm);
#pragma unroll
      for (int j = 0; j < 8; ++j) a[j] *= r;
      sig += __logf(mm);
    }
  }

  float* Ao = wsA + (size_t)(b * NC + c) * 64;
#pragma unroll
  for (int j = 0; j < 8; ++j) Ao[j * 8 + k] = a[j];  // row-major
  wsS[(b * NC + c) * 8 + k] = sig;
}

// ---------------------------------------------------------------------------
// Kernel 3: combine, 8 lanes per batch, next-chunk prefetch.
// ---------------------------------------------------------------------------
template <int NC>
__global__ __launch_bounds__(256) void combine_kernel(
    const float* __restrict__ score, const float* __restrict__ start_tr,
    const float* __restrict__ end_tr, const float* __restrict__ wsA,
    const float* __restrict__ wsS, const float* __restrict__ ws_num,
    float* __restrict__ out_loss) {
  int tid = blockIdx.x * blockDim.x + threadIdx.x;
  int j = tid & 7;
  int b = tid >> 3;

  float pj = __expf(start_tr[j] + score[(size_t)b * T * 8 + j]);
  float mm = pj;
#pragma unroll
  for (int m = 1; m < 8; m <<= 1) mm = fmaxf(mm, __shfl_xor(mm, m, 8));
  float tau = __logf(mm);
  pj *= __builtin_amdgcn_rcpf(mm);

  float eej = __expf(end_tr[j]);

  const float* Ab = wsA + (size_t)b * NC * 64;
  const float* Sb = wsS + (size_t)b * NC * 8;
  float4 r0 = *reinterpret_cast<const float4*>(Ab + j * 8);
  float4 r1 = *reinterpret_cast<const float4*>(Ab + j * 8 + 4);
  float sgj = Sb[j];

  for (int c = 0; c < NC; ++c) {
    float4 c0 = r0, c1 = r1;
    float sj = sgj;
    if (c + 1 < NC) {  // prefetch next chunk's row + scale
      const float* An = Ab + (size_t)(c + 1) * 64;
      r0 = *reinterpret_cast<const float4*>(An + j * 8);
      r1 = *reinterpret_cast<const float4*>(An + j * 8 + 4);
      sgj = Sb[(c + 1) * 8 + j];
    }
    float smax = sj;
#pragma unroll
    for (int m = 1; m < 8; m <<= 1) smax = fmaxf(smax, __shfl_xor(smax, m, 8));
    float wj = pj * __expf(sj - smax);
    float w[8];
#pragma unroll
    for (int i = 0; i < 8; ++i) w[i] = __shfl(wj, i, 8);
    float acc = c0.x * w[0];
    acc = fmaf(c0.y, w[1], acc);
    acc = fmaf(c0.z, w[2], acc);
    acc = fmaf(c0.w, w[3], acc);
    acc = fmaf(c1.x, w[4], acc);
    acc = fmaf(c1.y, w[5], acc);
    acc = fmaf(c1.z, w[6], acc);
    acc = fmaf(c1.w, w[7], acc);
    float mm2 = acc;
#pragma unroll
    for (int m = 1; m < 8; m <<= 1) mm2 = fmaxf(mm2, __shfl_xor(mm2, m, 8));
    tau += smax + __logf(mm2);
    pj = acc * __builtin_amdgcn_rcpf(mm2);
  }

  float term = pj * eej;
#pragma unroll
  for (int m = 1; m < 8; m <<= 1) term += __shfl_xor(term, m, 8);
  float logz = tau + __logf(term);

  float part = (j == 0) ? (logz - ws_num[b]) * (1.0f / (float)B) : 0.0f;
#pragma unroll
  for (int off = 32; off >= 1; off >>= 1) part += __shfl_down(part, off);
  if ((threadIdx.x & 63) == 0) atomicAdd(out_loss, part);
}

}  // namespace

extern "C" void kernel_launch(void* const* d_in, const int* in_sizes, int n_in,
                              void* d_out, int out_size, void* d_ws,
                              size_t ws_size, hipStream_t stream) {
  const float* log_p = (const float*)d_in[0];
  const float* score = (const float*)d_in[1];
  const float* trans = (const float*)d_in[2];
  const float* start_tr = (const float*)d_in[3];
  const float* end_tr = (const float*)d_in[4];
  const int* tags = (const int*)d_in[5];
  const int* seq_l = (const int*)d_in[6];
  float* out = (float*)d_out;  // out[0] = loss, out[1..] = pred_idx (as f32)

  // Workspace: A = B*NC*64, S = B*NC*8, num = B floats.
  size_t need64 = ((size_t)B * 64 * 72 + B) * sizeof(float);
  bool use64 = ws_size >= need64;

  int nc = use64 ? 64 : 32;
  float* wsA = (float*)d_ws;               // B*nc*64
  float* wsS = wsA + (size_t)B * nc * 64;  // B*nc*8
  float* wsNum = wsS + (size_t)B * nc * 8; // B

  hipMemsetAsync(wsNum, 0, B * sizeof(float), stream);
  hipMemsetAsync(out, 0, sizeof(float), stream);

  pred_num_kernel<<<(B * T / 4) / 256, 256, 0, stream>>>(
      log_p, score, trans, start_tr, end_tr, tags, seq_l, out + 1, wsNum);
  if (use64) {
    chunk_kernel<64, 6><<<(B * 64 * 8) / 256, 256, 0, stream>>>(
        score, trans, seq_l, wsA, wsS);
    combine_kernel<64><<<(B * 8) / 256, 256, 0, stream>>>(
        score, start_tr, end_tr, wsA, wsS, wsNum, out);
  } else {
    chunk_kernel<32, 5><<<(B * 32 * 8) / 256, 256, 0, stream>>>(
        score, trans, seq_l, wsA, wsS);
    combine_kernel<32><<<(B * 8) / 256, 256, 0, stream>>>(
        score, start_tr, end_tr, wsA, wsS, wsNum, out);
  }
}